// Round 8
// baseline (222.628 us; speedup 1.0000x reference)
//
#include <hip/hip_runtime.h>

// ADI diffusion B=16, C=8, S=128, 10 steps. Round 17: w-split occupancy.
// Cost model from rounds 6/7: w(in-kernel)=12.4us/step, o(dispatch)=5.5us.
// h-split (round 1) doubled occupancy but +33% Y work; w-split is ~free:
// Y is column-local, X needs only a +-2 col halo. 512 blocks x 512 thr,
// each owns (b, 8-row band, 64-col half). LDS = A+C = 64 rows x 75 cols x2
// = 38.4KB -> 2-4 blocks/CU (was 1). X1 parks in registers (extra barrier)
// instead of LDS region B; X2 recomputes coeffs from C (keeps VGPR <=128).
// 10 single-step dispatches (pair fusion is a wash until w shrinks).

constexpr int S_ = 128;
constexpr float EPSF = 1e-6f;
constexpr int RSW = 75;     // A/C row stride: 75%32=11, gcd(11,32)=1 -> <=2 lanes/bank
constexpr int RST = 129;    // head staging stride (proven conflict-free)
constexpr int OFF_A  = 0;
constexpr int OFF_C  = 64 * RSW;    // 4800
constexpr int OFF_X0 = 96 * RST;    // head only: x@0 window, 96 rows x RSW

template <int N>
__device__ __forceinline__ void jrunN(const float (&e)[N], const float (&g)[N],
                                      float (&o)[N - 4]) {
    // Jacobi-2 == fixed 5-point formula, stencil radius 2 per output.
    float x1[N];
    #pragma unroll
    for (int i = 1; i <= N - 2; ++i) x1[i] = fmaf(g[i], e[i - 1] + e[i + 1], e[i]);
    #pragma unroll
    for (int i = 2; i <= N - 3; ++i) o[i - 2] = fmaf(g[i], x1[i - 1] + x1[i + 1], e[i]);
}

template <bool HEAD, bool LASTK>
__global__ __launch_bounds__(512, 4) void step_kernel(
    const float* __restrict__ usrc, float* __restrict__ udst,
    const float* __restrict__ ab, const float* __restrict__ atc,
    const float* __restrict__ bbeta, const float* __restrict__ btc,
    const float* __restrict__ cm, float t_y, float t_x)
{
    constexpr int POOL = HEAD ? (96 * RST + 96 * RSW) : (128 * RSW);
    __shared__ float sP[POOL];
    const int tid  = threadIdx.x;
    const int rem  = blockIdx.x & 31;
    const int b    = blockIdx.x >> 5;
    const int h0   = (rem >> 1) << 3;       // 16 h-chunks of 8 rows
    const int wh   = rem & 1;               // w half: cols [wh*64, wh*64+64)
    const int woff = wh * 64 - 4;           // A/C col aw <-> global col woff+aw

    if (HEAD) {
        // stage 96 rows x 128 cols pristine u (full width; one-time cost)
        #pragma unroll
        for (int m = 0; m < 24; ++m) {
            const int task = tid + 512 * m;
            const int rr = task >> 7, w = task & 127;
            const int c = rr / 12, hh = rr % 12;
            const int gh = h0 - 2 + hh;
            float v = 0.f;
            if (gh >= 0 && gh < S_) v = usrc[((b * 8 + c) * S_ + gh) * S_ + w];
            sP[rr * RST + w] = v;
        }
        __syncthreads();
        // channel mix in place (1536 points, 3/thread)
        {
            float M[64];
            #pragma unroll
            for (int i = 0; i < 64; ++i) M[i] = cm[i];
            #pragma unroll
            for (int m = 0; m < 3; ++m) {
                const int p = tid + 512 * m;
                const int hh = p >> 7, w = p & 127;
                float v[8], o[8];
                #pragma unroll
                for (int c = 0; c < 8; ++c) v[c] = sP[(c * 12 + hh) * RST + w];
                #pragma unroll
                for (int dd = 0; dd < 8; ++dd) {
                    float a = 0.f;
                    #pragma unroll
                    for (int c = 0; c < 8; ++c) a = fmaf(M[dd * 8 + c], v[c], a);
                    o[dd] = a;
                }
                #pragma unroll
                for (int c = 0; c < 8; ++c) sP[(c * 12 + hh) * RST + w] = o[c];
            }
        }
        __syncthreads();
        // x@0 (alpha=clip(ab), t=0): 96 rows x 16 full-width runs, 3/thread;
        // store only cols inside this block's window -> X0.
        #pragma unroll
        for (int m = 0; m < 3; ++m) {
            const int task = tid + 512 * m;
            const int rr = task % 96, wr = task / 96;
            const int c = rr / 12, hh = rr % 12;
            const int gh = h0 - 2 + hh;
            const bool rowin = (gh >= 0 && gh < S_);
            const int w0 = wr * 8;
            float e[12], g[12];
            #pragma unroll
            for (int j = 0; j < 12; ++j) {
                const int wj = w0 - 2 + j;
                const bool win = (wj >= 0 && wj < S_);
                const float dv = win ? sP[rr * RST + wj] : 0.f;
                float co = 0.f;
                if (rowin && win) {
                    float al = ab[(c * S_ + gh) * S_ + wj];
                    co = fminf(fmaxf(al, EPSF), 10.f) * 0.0005f;
                }
                const float nb = (wj == 0 || wj == S_ - 1) ? 1.f : 2.f;
                const float rb = __builtin_amdgcn_rcpf(fmaf(nb, co, 1.f) + EPSF);
                e[j] = rb * dv; g[j] = rb * co;
            }
            float o[8]; jrunN<12>(e, g, o);
            #pragma unroll
            for (int i = 0; i < 8; ++i) {
                const int rel = w0 + i - woff;
                if (rel >= 0 && rel < RSW) sP[OFF_X0 + rr * RSW + rel] = o[i];
            }
        }
        __syncthreads();
    }

    // ---- Y stage: 8c x 75 cols = 600 col-tasks; 12-in -> 8-out along h -> A.
    #pragma unroll
    for (int m = 0; m < 2; ++m) {
        const int task = tid + 512 * m;
        if (task < 600) {
            const int c = task / RSW, ws = task % RSW;
            const int gw = woff + ws;
            const bool wvalid = (gw >= 0 && gw < S_);
            const int gwc = wvalid ? gw : 0;
            float e[12], g[12];
            #pragma unroll
            for (int hh = 0; hh < 12; ++hh) {
                const int gh = h0 - 2 + hh;
                const bool inr = (gh >= 0 && gh < S_);
                const int ghc = inr ? gh : 0;
                float dv = 0.f;
                if (inr && wvalid) {
                    if (HEAD) dv = sP[OFF_X0 + (c * 12 + hh) * RSW + ws];
                    else      dv = usrc[((b * 8 + c) * S_ + ghc) * S_ + gwc];
                }
                const int gc = (c * S_ + ghc) * S_ + gwc;
                float be = fmaf(btc[gc], t_y, bbeta[gc]);
                be = fminf(fmaxf(be, EPSF), 10.f);
                const float co = inr ? be * 0.001f : 0.f;
                const float nb = (gh == 0 || gh == S_ - 1) ? 1.f : 2.f;
                const float rb = __builtin_amdgcn_rcpf(fmaf(nb, co, 1.f) + EPSF);
                e[hh] = rb * dv; g[hh] = rb * co;
            }
            float o[8]; jrunN<12>(e, g, o);
            #pragma unroll
            for (int i = 0; i < 8; ++i) sP[OFF_A + (c * 8 + i) * RSW + ws] = o[i];
        }
    }
    // x-coeff into C: 64 rows x 75 cols, scalar coalesced (conflict-free)
    #pragma unroll
    for (int m = 0; m < 10; ++m) {
        const int task = tid + 512 * m;
        if (task < 4800) {
            const int r = task / RSW, wc = task % RSW;
            const int gw = woff + wc;
            float al = 0.f;
            if (gw >= 0 && gw < S_) {
                const int c = r >> 3, ho = r & 7;
                const int gc = (c * S_ + h0 + ho) * S_ + gw;
                al = fmaf(atc[gc], t_x, ab[gc]);
                al = fminf(fmaxf(al, EPSF), 10.f) * 0.0005f;
            }
            sP[OFF_C + r * RSW + wc] = al;
        }
    }
    __syncthreads();

    if (LASTK) {
        // final x-solve (no mix follows): 8 aligned runs -> global out
        const int r = tid & 63, wr = tid >> 6;
        const int c = r >> 3, ho = r & 7;
        const int gw0 = wh * 64 + wr * 8;
        float e[12], g[12];
        #pragma unroll
        for (int j = 0; j < 12; ++j) {
            const int gj = gw0 - 2 + j;
            const int aw = wr * 8 + 2 + j;
            const bool win = (gj >= 0 && gj < S_);
            const float co = win ? sP[OFF_C + r * RSW + aw] : 0.f;
            const float dv = win ? sP[OFF_A + r * RSW + aw] : 0.f;
            const float nb = (gj == 0 || gj == S_ - 1) ? 1.f : 2.f;
            const float rb = __builtin_amdgcn_rcpf(fmaf(nb, co, 1.f) + EPSF);
            e[j] = rb * dv; g[j] = rb * co;
        }
        float o[8]; jrunN<12>(e, g, o);
        float4* dst4 = (float4*)&udst[((b * 8 + c) * S_ + h0 + ho) * S_ + gw0];
        dst4[0] = make_float4(o[0], o[1], o[2], o[3]);
        dst4[1] = make_float4(o[4], o[5], o[6], o[7]);
    } else {
        // X1: 64 rows x 9 runs (covers out cols [-2,65] for mix+X2), park in regs
        float xo[2][8];
        #pragma unroll
        for (int m = 0; m < 2; ++m) {
            const int task = tid + 512 * m;
            if (task < 576) {
                const int r = task & 63, wr = task >> 6;   // wr in [0,9)
                const int w0g = wh * 64 - 2 + wr * 8;
                float e[12], g[12];
                #pragma unroll
                for (int j = 0; j < 12; ++j) {
                    const int gj = w0g - 2 + j;
                    const int aw = wr * 8 + j;
                    const bool win = (gj >= 0 && gj < S_);
                    const float co = win ? sP[OFF_C + r * RSW + aw] : 0.f;
                    const float dv = win ? sP[OFF_A + r * RSW + aw] : 0.f;
                    const float nb = (gj == 0 || gj == S_ - 1) ? 1.f : 2.f;
                    const float rb = __builtin_amdgcn_rcpf(fmaf(nb, co, 1.f) + EPSF);
                    e[j] = rb * dv; g[j] = rb * co;
                }
                jrunN<12>(e, g, xo[m]);
            }
        }
        __syncthreads();              // all A reads done
        #pragma unroll
        for (int m = 0; m < 2; ++m) { // write xo back into A (cols aw 2..73)
            const int task = tid + 512 * m;
            if (task < 576) {
                const int r = task & 63, wr = task >> 6;
                #pragma unroll
                for (int i = 0; i < 8; ++i)
                    sP[OFF_A + r * RSW + wr * 8 + 2 + i] = xo[m][i];
            }
        }
        __syncthreads();
        // mix in place on A: 8 ho x 75 cols = 600 points
        {
            float M[64];
            #pragma unroll
            for (int i = 0; i < 64; ++i) M[i] = cm[i];
            #pragma unroll
            for (int m = 0; m < 2; ++m) {
                const int task = tid + 512 * m;
                if (task < 600) {
                    const int ho = task / RSW, aw = task % RSW;
                    float v[8], o[8];
                    #pragma unroll
                    for (int c = 0; c < 8; ++c) v[c] = sP[OFF_A + (c * 8 + ho) * RSW + aw];
                    #pragma unroll
                    for (int dd = 0; dd < 8; ++dd) {
                        float a = 0.f;
                        #pragma unroll
                        for (int c = 0; c < 8; ++c) a = fmaf(M[dd * 8 + c], v[c], a);
                        o[dd] = a;
                    }
                    #pragma unroll
                    for (int c = 0; c < 8; ++c) sP[OFF_A + (c * 8 + ho) * RSW + aw] = o[c];
                }
            }
        }
        __syncthreads();
        // X2: 8 aligned runs, same t_x (coeffs re-read from C) -> global
        const int r = tid & 63, wr = tid >> 6;
        const int c = r >> 3, ho = r & 7;
        const int gw0 = wh * 64 + wr * 8;
        float e[12], g[12];
        #pragma unroll
        for (int j = 0; j < 12; ++j) {
            const int gj = gw0 - 2 + j;
            const int aw = wr * 8 + 2 + j;
            const bool win = (gj >= 0 && gj < S_);
            const float co = win ? sP[OFF_C + r * RSW + aw] : 0.f;
            const float dv = win ? sP[OFF_A + r * RSW + aw] : 0.f;
            const float nb = (gj == 0 || gj == S_ - 1) ? 1.f : 2.f;
            const float rb = __builtin_amdgcn_rcpf(fmaf(nb, co, 1.f) + EPSF);
            e[j] = rb * dv; g[j] = rb * co;
        }
        float o[8]; jrunN<12>(e, g, o);
        float4* dst4 = (float4*)&udst[((b * 8 + c) * S_ + h0 + ho) * S_ + gw0];
        dst4[0] = make_float4(o[0], o[1], o[2], o[3]);
        dst4[1] = make_float4(o[4], o[5], o[6], o[7]);
    }
}

extern "C" void kernel_launch(void* const* d_in, const int* in_sizes, int n_in,
                              void* d_out, int out_size, void* d_ws, size_t ws_size,
                              hipStream_t stream) {
    const float* u_in = (const float*)d_in[0];
    const float* ab   = (const float*)d_in[1];
    const float* bbta = (const float*)d_in[2];
    const float* atc  = (const float*)d_in[3];
    const float* btc  = (const float*)d_in[4];
    const float* cm   = (const float*)d_in[5];
    float* uo  = (float*)d_out;
    float* uw1 = (float*)d_ws;                        // ping
    float* uw2 = (float*)d_ws + (16 * 8 * 128 * 128); // pong (+8 MiB)

    const dim3 g(512), blk(512);
    const float dt2 = 0.0005f;

    step_kernel<true, false><<<g, blk, 0, stream>>>(u_in, uw1, ab, atc, bbta, btc, cm,
                                                    1 * dt2, 2 * dt2);
    const float* s = uw1; float* d = uw2;
    for (int k = 1; k <= 8; ++k) {
        step_kernel<false, false><<<g, blk, 0, stream>>>(s, d, ab, atc, bbta, btc, cm,
                                                         (2 * k + 1) * dt2, (2 * k + 2) * dt2);
        const float* ns = d;
        d = (d == uw2) ? uw1 : uw2;
        s = ns;
    }
    step_kernel<false, true><<<g, blk, 0, stream>>>(s, uo, ab, atc, bbta, btc, cm,
                                                    19 * dt2, 20 * dt2);
}

// Round 9
// 166.480 us; speedup vs baseline: 1.3373x; 1.3373x over previous
//
#include <hip/hip_runtime.h>
#include <hip/hip_fp16.h>

// ADI diffusion B=16, C=8, S=128, 10 steps. Round 18: fp16 traffic cut.
// Evidence r1/r8: occupancy null x3, VALUBusy ~24%, no conflicts, coalesced
// -> steps are far-memory-latency bound with capped per-CU MLP. Lever:
// halve the cache-line count. (1) ping-pong u stored as __half (8->4.2MB);
// (2) one precompute kernel bakes all 21 coefficient fields (Y/X per step +
// x@0) as __half2{g, rb-1} (4B/point vs 8B raw) -> also deletes the
// clamp+fma+rcp chain from every tap. Step structure = proven round-0
// kernel (256 blocks x 512 thr, same phases/barriers/LDS maps).

constexpr int S_  = 128;
constexpr int RS  = 129;            // padded LDS row stride
constexpr float EPSF = 1e-6f;
constexpr int CSS = 8 * 128 * 128;  // 131072 points per coeff field

__device__ __forceinline__ float2 decf(uint cb) {
    __half2 h = *reinterpret_cast<__half2*>(&cb);
    return __half22float2(h);       // .x = g, .y = rb-1
}

template <int N>
__device__ __forceinline__ void jrunN(const float (&e)[N], const float (&g)[N],
                                      float (&o)[N - 4]) {
    // Jacobi-2 == fixed 5-point formula, stencil radius 2 per output.
    float x1[N];
    #pragma unroll
    for (int i = 1; i <= N - 2; ++i) x1[i] = fmaf(g[i], e[i - 1] + e[i + 1], e[i]);
    #pragma unroll
    for (int i = 2; i <= N - 3; ++i) o[i - 2] = fmaf(g[i], x1[i - 1] + x1[i + 1], e[i]);
}

// ---- coefficient precompute: fid 0..9 = Y@t_y(k); 10..19 = X@t_x(k); 20 = X@t=0
__global__ __launch_bounds__(256) void coef_kernel(
    const float* __restrict__ ab, const float* __restrict__ atc,
    const float* __restrict__ bb, const float* __restrict__ btc,
    __half2* __restrict__ cf)
{
    for (int gc = blockIdx.x * 256 + threadIdx.x; gc < CSS; gc += gridDim.x * 256) {
        const int w = gc & 127, h = (gc >> 7) & 127;
        const float abv = ab[gc], atv = atc[gc], bbv = bb[gc], btv = btc[gc];
        const float nbY = (h == 0 || h == S_ - 1) ? 1.f : 2.f;
        const float nbX = (w == 0 || w == S_ - 1) ? 1.f : 2.f;
        for (int k = 0; k < 10; ++k) {
            const float ty = (2 * k + 1) * 0.0005f;
            const float tx = (2 * k + 2) * 0.0005f;
            float be = fminf(fmaxf(fmaf(btv, ty, bbv), EPSF), 10.f);
            float co = be * 0.001f;
            float rb = __builtin_amdgcn_rcpf(fmaf(nbY, co, 1.f) + EPSF);
            cf[k * CSS + gc] = __floats2half2_rn(rb * co, rb - 1.f);
            float al = fminf(fmaxf(fmaf(atv, tx, abv), EPSF), 10.f);
            co = al * 0.0005f;
            rb = __builtin_amdgcn_rcpf(fmaf(nbX, co, 1.f) + EPSF);
            cf[(10 + k) * CSS + gc] = __floats2half2_rn(rb * co, rb - 1.f);
        }
        float al = fminf(fmaxf(abv, EPSF), 10.f);
        float co = al * 0.0005f;
        float rb = __builtin_amdgcn_rcpf(fmaf(nbX, co, 1.f) + EPSF);
        cf[20 * CSS + gc] = __floats2half2_rn(rb * co, rb - 1.f);
    }
}

template <bool HEAD, bool LASTK>
__global__ __launch_bounds__(512, 2) void step_kernel(
    const void* __restrict__ usrc_, void* __restrict__ udst_,
    const __half2* __restrict__ cfy, const __half2* __restrict__ cfx,
    const __half2* __restrict__ cfx0, const float* __restrict__ cm)
{
    constexpr int POOL   = HEAD ? 288 * RS : 192 * RS;   // 148.6KB / 99KB
    constexpr int OFF_A  = 0;                            // 64 rows: Y-out / mix-out
    constexpr int OFF_B  = 64 * RS;                      // 64 rows: x1 park
    constexpr int OFF_CP = HEAD ? 192 * RS : 128 * RS;   // 64 rows: packed x-coeff
    constexpr int OFF_X0 = 96 * RS;                      // head: x@0 out (96 rows)
    __shared__ float sP[POOL];
    const int tid = threadIdx.x;
    const int b   = blockIdx.x >> 4;
    const int h0  = (blockIdx.x & 15) << 3;

    if (HEAD) {
        const float* u0 = (const float*)usrc_;
        // stage 12-row pristine tile into ST=[0,96) (zeros outside domain)
        #pragma unroll
        for (int m = 0; m < 2; ++m) {
            const int col = tid + 512 * m;
            const int c = col >> 7, w = col & 127;
            #pragma unroll
            for (int hh = 0; hh < 12; ++hh) {
                const int gh = h0 - 2 + hh;
                float v = 0.f;
                if (gh >= 0 && gh < S_) v = u0[((b * 8 + c) * S_ + gh) * S_ + w];
                sP[(c * 12 + hh) * RS + w] = v;
            }
        }
        // stage packed x@0 coeffs into [192,288) (96 rows; clamped rows ok)
        #pragma unroll
        for (int m = 0; m < 12; ++m) {
            const int task = tid + 512 * m;         // 6144
            const int r = task >> 6, col2 = task & 63;
            const int c = r / 12, hh = r % 12;
            int gh = h0 - 2 + hh; gh = gh < 0 ? 0 : (gh >= S_ ? S_ - 1 : gh);
            const uint2 v = ((const uint2*)cfx0)[(c * S_ + gh) * 64 + col2];
            sP[OFF_CP + r * RS + col2 * 2]     = __uint_as_float(v.x);
            sP[OFF_CP + r * RS + col2 * 2 + 1] = __uint_as_float(v.y);
        }
        __syncthreads();
        // channel mix in place on ST
        {
            float M[64];
            #pragma unroll
            for (int i = 0; i < 64; ++i) M[i] = cm[i];
            #pragma unroll
            for (int m = 0; m < 3; ++m) {
                const int p = tid + 512 * m;
                const int hh = p >> 7, w = p & 127;
                float v[8], o[8];
                #pragma unroll
                for (int c = 0; c < 8; ++c) v[c] = sP[(c * 12 + hh) * RS + w];
                #pragma unroll
                for (int dd = 0; dd < 8; ++dd) {
                    float a = 0.f;
                    #pragma unroll
                    for (int c = 0; c < 8; ++c) a = fmaf(M[dd * 8 + c], v[c], a);
                    o[dd] = a;
                }
                #pragma unroll
                for (int c = 0; c < 8; ++c) sP[(c * 12 + hh) * RS + w] = o[c];
            }
        }
        __syncthreads();
        // x@0: 96 rows x 16 runs, 3/thread -> X0
        #pragma unroll
        for (int m = 0; m < 3; ++m) {
            const int task = tid + 512 * m;
            const int r96 = task % 96, wr = task / 96;
            const int c = r96 / 12, hh = r96 % 12;
            const int gh = h0 - 2 + hh;
            const bool rowin = (gh >= 0 && gh < S_);
            const int w0 = wr * 8;
            float e[12], g[12];
            #pragma unroll
            for (int j = 0; j < 12; ++j) {
                const int wj = w0 - 2 + j;
                const bool win = (wj >= 0 && wj < S_);
                const float dv = win ? sP[r96 * RS + wj] : 0.f;  // ST: 0 on OOR rows
                const uint cb = (rowin && win)
                    ? __float_as_uint(sP[OFF_CP + r96 * RS + wj]) : 0u;
                const float2 f = decf(cb);
                e[j] = (1.f + f.y) * dv;
                g[j] = f.x;
            }
            float o[8]; jrunN<12>(e, g, o);
            #pragma unroll
            for (int i = 0; i < 8; ++i) sP[OFF_X0 + r96 * RS + w0 + i] = o[i];
        }
        __syncthreads();
    }

    // ---- Y stage: 1024 (c,w) cols, 2/thread; 12-in -> 8-out -> A.
    const __half* us = (const __half*)usrc_;
    #pragma unroll
    for (int m = 0; m < 2; ++m) {
        const int col = tid + 512 * m;
        const int c = col >> 7, w = col & 127;
        float e[12], g[12];
        #pragma unroll
        for (int hh = 0; hh < 12; ++hh) {
            const int gh = h0 - 2 + hh;
            const bool inr = (gh >= 0 && gh < S_);
            const int ghc = inr ? gh : 0;
            float dv;
            if (HEAD) dv = sP[OFF_X0 + (c * 12 + hh) * RS + w];  // 0 on OOR rows
            else      dv = inr ? __half2float(us[((b * 8 + c) * S_ + ghc) * S_ + w]) : 0.f;
            const __half2 cy = cfy[(c * S_ + ghc) * S_ + w];
            const float2 f = __half22float2(cy);
            e[hh] = (1.f + f.y) * dv;
            g[hh] = inr ? f.x : 0.f;
        }
        float o[8]; jrunN<12>(e, g, o);
        #pragma unroll
        for (int i = 0; i < 8; ++i) sP[OFF_A + (c * 8 + i) * RS + w] = o[i];
    }
    // stage packed x-coeff into CP (64 rows, uint2-coalesced)
    #pragma unroll
    for (int m = 0; m < 8; ++m) {
        const int task = tid + 512 * m;             // 4096
        const int r = task >> 6, col2 = task & 63;
        const int c = r >> 3, ho = r & 7;
        const uint2 v = ((const uint2*)cfx)[(c * S_ + h0 + ho) * 64 + col2];
        sP[OFF_CP + r * RS + col2 * 2]     = __uint_as_float(v.x);
        sP[OFF_CP + r * RS + col2 * 2 + 1] = __uint_as_float(v.y);
    }
    __syncthreads();

    // ---- X1: 64 rows x 16 runs, 2/thread; cache rb/g in regs for X2.
    float rbk[2][12], gk[2][12], xo[2][8];
    #pragma unroll
    for (int m = 0; m < 2; ++m) {
        const int run = tid + 512 * m;
        const int r = run & 63, wr = run >> 6;
        const int w0 = wr * 8;
        float e[12];
        #pragma unroll
        for (int j = 0; j < 12; ++j) {
            const int wj = w0 - 2 + j;
            const bool win = (wj >= 0 && wj < S_);
            const float dv = win ? sP[OFF_A + r * RS + wj] : 0.f;
            const uint cb = win ? __float_as_uint(sP[OFF_CP + r * RS + wj]) : 0u;
            const float2 f = decf(cb);
            rbk[m][j] = 1.f + f.y; gk[m][j] = f.x;
            e[j] = rbk[m][j] * dv;
        }
        jrunN<12>(e, gk[m], xo[m]);
    }

    if (LASTK) {
        // final step: no mix after; xo -> fp32 d_out
        float* ud = (float*)udst_;
        #pragma unroll
        for (int m = 0; m < 2; ++m) {
            const int run = tid + 512 * m;
            const int r = run & 63, wr = run >> 6;
            const int c = r >> 3, ho = r & 7;
            float4* dst4 = (float4*)&ud[((b * 8 + c) * S_ + h0 + ho) * S_ + wr * 8];
            dst4[0] = make_float4(xo[m][0], xo[m][1], xo[m][2], xo[m][3]);
            dst4[1] = make_float4(xo[m][4], xo[m][5], xo[m][6], xo[m][7]);
        }
    } else {
        #pragma unroll
        for (int m = 0; m < 2; ++m) {
            const int run = tid + 512 * m;
            const int r = run & 63, w0 = (run >> 6) * 8;
            #pragma unroll
            for (int i = 0; i < 8; ++i) sP[OFF_B + r * RS + w0 + i] = xo[m][i];
        }
        __syncthreads();
        // mix: read B, write A
        float M[64];
        #pragma unroll
        for (int i = 0; i < 64; ++i) M[i] = cm[i];
        #pragma unroll
        for (int m = 0; m < 2; ++m) {
            const int p = tid + 512 * m;
            const int ho = p >> 7, w = p & 127;
            float v[8], o[8];
            #pragma unroll
            for (int c = 0; c < 8; ++c) v[c] = sP[OFF_B + (c * 8 + ho) * RS + w];
            #pragma unroll
            for (int dd = 0; dd < 8; ++dd) {
                float a = 0.f;
                #pragma unroll
                for (int c = 0; c < 8; ++c) a = fmaf(M[dd * 8 + c], v[c], a);
                o[dd] = a;
            }
            #pragma unroll
            for (int c = 0; c < 8; ++c) sP[OFF_A + (c * 8 + ho) * RS + w] = o[c];
        }
        __syncthreads();
        // X2: same runs, reg-cached coeffs -> fp16 store
        __half* ud = (__half*)udst_;
        #pragma unroll
        for (int m = 0; m < 2; ++m) {
            const int run = tid + 512 * m;
            const int r = run & 63, wr = run >> 6;
            const int w0 = wr * 8;
            const int c = r >> 3, ho = r & 7;
            float e[12];
            #pragma unroll
            for (int j = 0; j < 12; ++j) {
                const int wj = w0 - 2 + j;
                const bool win = (wj >= 0 && wj < S_);
                const float dv = win ? sP[OFF_A + r * RS + wj] : 0.f;
                e[j] = rbk[m][j] * dv;
            }
            float o[8]; jrunN<12>(e, gk[m], o);
            __half2* d2 = (__half2*)&ud[((b * 8 + c) * S_ + h0 + ho) * S_ + w0];
            d2[0] = __floats2half2_rn(o[0], o[1]);
            d2[1] = __floats2half2_rn(o[2], o[3]);
            d2[2] = __floats2half2_rn(o[4], o[5]);
            d2[3] = __floats2half2_rn(o[6], o[7]);
        }
    }
}

extern "C" void kernel_launch(void* const* d_in, const int* in_sizes, int n_in,
                              void* d_out, int out_size, void* d_ws, size_t ws_size,
                              hipStream_t stream) {
    const float* u_in = (const float*)d_in[0];
    const float* ab   = (const float*)d_in[1];
    const float* bbta = (const float*)d_in[2];
    const float* atc  = (const float*)d_in[3];
    const float* btc  = (const float*)d_in[4];
    const float* cm   = (const float*)d_in[5];
    float* uo = (float*)d_out;
    __half*  h1 = (__half*)d_ws;                                   // 4.2MB
    __half*  h2 = (__half*)((char*)d_ws + (8u << 20));             // 4.2MB
    __half2* cf = (__half2*)((char*)d_ws + (16u << 20));           // 11MB

    coef_kernel<<<dim3(512), dim3(256), 0, stream>>>(ab, atc, bbta, btc, cf);

    const dim3 g(256), blk(512);
    // k=0 (head): u0 fp32 -> h1 fp16
    step_kernel<true, false><<<g, blk, 0, stream>>>(u_in, h1, cf + 0 * CSS,
                                                    cf + 10 * CSS, cf + 20 * CSS, cm);
    const __half* s = h1; __half* d = h2;
    for (int k = 1; k <= 8; ++k) {
        step_kernel<false, false><<<g, blk, 0, stream>>>(s, d, cf + k * CSS,
                                                         cf + (10 + k) * CSS, cf, cm);
        const __half* ns = d;
        d = (d == h2) ? h1 : h2;
        s = ns;
    }
    // k=9: fp16 -> fp32 d_out (no mix)
    step_kernel<false, true><<<g, blk, 0, stream>>>(s, uo, cf + 9 * CSS,
                                                    cf + 19 * CSS, cf, cm);
}